// Round 2
// baseline (1061.499 us; speedup 1.0000x reference)
//
#include <hip/hip_runtime.h>
#include <hip/hip_bf16.h>

#define ALPHA 0.01f

typedef __attribute__((ext_vector_type(8))) __bf16 bf16x8;
typedef __attribute__((ext_vector_type(4))) float f32x4;

#define BATCH 32
#define P1H 97
#define P1W 127
#define P2W 62
#define FLAT 186496
#define CHUNK 512
#define NCHUNK 365            // ceil(186496/512)
#define PSTRIDE1 16448        // 32*512 + 64 pad (floats) — break pow-2 stride
#define PSTRIDE2 8256         // 32*256 + 64 pad

static __device__ __forceinline__ unsigned short f2bf(float x) {
  union { float f; unsigned u; } c; c.f = x;
  unsigned r = c.u + 0x7fffu + ((c.u >> 16) & 1u);
  return (unsigned short)(r >> 16);
}

// ---------------- conv1 (3x3x1->32) + ReLU + 2x2 maxpool, out bf16 ----------------
__global__ __launch_bounds__(256) void conv1_pool(const float* __restrict__ x,
    const float* __restrict__ w1, const float* __restrict__ b1,
    unsigned short* __restrict__ p1) {
  int pid = blockIdx.x * 256 + threadIdx.x;
  if (pid >= BATCH * P1H * P1W) return;
  int b = pid / (P1H * P1W);
  int rem = pid - b * (P1H * P1W);
  int ph = rem / P1W;
  int pw = rem - ph * P1W;
  const float* xb = x + ((b * 197 + 2 * ph) * 256 + 2 * pw);
  float in[4][4];
#pragma unroll
  for (int r = 0; r < 4; ++r) {
    float2 v0 = *reinterpret_cast<const float2*>(xb + r * 256);
    float2 v1 = *reinterpret_cast<const float2*>(xb + r * 256 + 2);
    in[r][0] = v0.x; in[r][1] = v0.y; in[r][2] = v1.x; in[r][3] = v1.y;
  }
  unsigned pk[16];
#pragma unroll
  for (int c = 0; c < 32; ++c) {
    float s00 = b1[c], s01 = s00, s10 = s00, s11 = s00;
#pragma unroll
    for (int ky = 0; ky < 3; ++ky)
#pragma unroll
      for (int kx = 0; kx < 3; ++kx) {
        float w = w1[(ky * 3 + kx) * 32 + c];
        s00 = fmaf(in[ky][kx], w, s00);
        s01 = fmaf(in[ky][kx + 1], w, s01);
        s10 = fmaf(in[ky + 1][kx], w, s10);
        s11 = fmaf(in[ky + 1][kx + 1], w, s11);
      }
    float m = fmaxf(fmaxf(s00, s01), fmaxf(s10, s11));
    m = fmaxf(m, 0.0f);
    unsigned short u = f2bf(m);
    if (c & 1) pk[c >> 1] |= ((unsigned)u) << 16;
    else pk[c >> 1] = (unsigned)u;
  }
  uint4* dst = reinterpret_cast<uint4*>(p1 + (size_t)pid * 32);
#pragma unroll
  for (int g = 0; g < 4; ++g)
    dst[g] = make_uint4(pk[g * 4], pk[g * 4 + 1], pk[g * 4 + 2], pk[g * 4 + 3]);
}

// ---------------- repack conv2 weights (3,3,32,64) f32 -> bf16 MFMA B-fragments ----
__global__ __launch_bounds__(256) void repack_w2(const float* __restrict__ w2,
                                                 unsigned short* __restrict__ bpack) {
  int o = blockIdx.x * 256 + threadIdx.x;
  if (o >= 9 * 4 * 512) return;
  int f = o >> 9;
  int within = o & 511;
  int lane = within >> 3, j = within & 7;
  int tap = f >> 2, nf = f & 3;
  int k = ((lane >> 4) << 3) + j;
  int n = nf * 16 + (lane & 15);
  bpack[o] = f2bf(w2[(tap * 32 + k) * 64 + n]);
}

// ---------------- conv2 (3x3x32->64) MFMA + bias + ReLU + 2x2 maxpool -> h f32 -----
__global__ __launch_bounds__(256) void conv2_pool(const unsigned short* __restrict__ p1,
    const unsigned short* __restrict__ bpack, const float* __restrict__ b2,
    float* __restrict__ h) {
  __shared__ alignas(16) unsigned char lds_buf[65536];
  int prow = blockIdx.x, b = blockIdx.y;
  int tid = threadIdx.x;
  int lane = tid & 63, wid = tid >> 6;
  {
    const uint4* src = reinterpret_cast<const uint4*>(bpack);
    uint4* dst = reinterpret_cast<uint4*>(lds_buf);
    for (int i = tid; i < 2304; i += 256) dst[i] = src[i];
  }
  __syncthreads();
  int row = lane & 15, kg = lane >> 4;
  int rowbase[4];
  int coff[4][3];
#pragma unroll
  for (int mf = 0; mf < 4; ++mf) {
    int m = wid * 64 + mf * 16 + row;
    int cro = m >> 7, cc = m & 127;
    rowbase[mf] = ((b * 97 + 2 * prow + cro) * 127) * 32 + kg * 8;
#pragma unroll
    for (int kx = 0; kx < 3; ++kx) {
      int ic = cc + kx; if (ic > 126) ic = 126;
      coff[mf][kx] = ic * 32;
    }
  }
  f32x4 acc[4][4];
#pragma unroll
  for (int i = 0; i < 4; ++i)
#pragma unroll
    for (int j = 0; j < 4; ++j) acc[i][j] = (f32x4){0.f, 0.f, 0.f, 0.f};

  const bf16x8* bl = reinterpret_cast<const bf16x8*>(lds_buf);
#pragma unroll
  for (int ky = 0; ky < 3; ++ky) {
#pragma unroll
    for (int kx = 0; kx < 3; ++kx) {
      int tap = ky * 3 + kx;
      bf16x8 a[4];
#pragma unroll
      for (int mf = 0; mf < 4; ++mf) {
        int addr = rowbase[mf] + ky * (127 * 32) + coff[mf][kx];
        a[mf] = *reinterpret_cast<const bf16x8*>(p1 + addr);
      }
      bf16x8 bf[4];
#pragma unroll
      for (int nf = 0; nf < 4; ++nf) bf[nf] = bl[(tap * 4 + nf) * 64 + lane];
#pragma unroll
      for (int nf = 0; nf < 4; ++nf)
#pragma unroll
        for (int mf = 0; mf < 4; ++mf)
          acc[mf][nf] = __builtin_amdgcn_mfma_f32_16x16x32_bf16(a[mf], bf[nf], acc[mf][nf], 0, 0, 0);
    }
  }
  __syncthreads();
  float* stage = reinterpret_cast<float*>(lds_buf);
#pragma unroll
  for (int mf = 0; mf < 4; ++mf)
#pragma unroll
    for (int nf = 0; nf < 4; ++nf) {
      int ch = nf * 16 + (lane & 15);
      float bias = b2[ch];
#pragma unroll
      for (int j = 0; j < 4; ++j) {
        int m = wid * 64 + mf * 16 + (lane >> 4) * 4 + j;
        float v = acc[mf][nf][j] + bias;
        stage[m * 64 + ch] = fmaxf(v, 0.f);
      }
    }
  __syncthreads();
  float* hb = h + (size_t)b * FLAT + prow * (P2W * 64);
  for (int o = tid; o < P2W * 64; o += 256) {
    int pw = o >> 6, ch = o & 63;
    int c0 = 2 * pw;
    float v = fmaxf(fmaxf(stage[c0 * 64 + ch], stage[(c0 + 1) * 64 + ch]),
                    fmaxf(stage[(128 + c0) * 64 + ch], stage[(129 + c0) * 64 + ch]));
    hb[o] = v;
  }
}

// ---------------- big skinny GEMM: one column/thread, h via wave-uniform loads -----
// partial[chunk][m][n] with padded chunk stride CSTRIDE (non-pow2)
template <int N, int CSTRIDE>
__global__ __launch_bounds__(N) void gemm_big(const float* __restrict__ W,
    const float* __restrict__ h, float* __restrict__ partial) {
  int tid = threadIdx.x;
  int k0 = blockIdx.x * CHUNK;
  int kend = k0 + CHUNK; if (kend > FLAT) kend = FLAT;
  float acc[32];
#pragma unroll
  for (int m = 0; m < 32; ++m) acc[m] = 0.f;
#pragma unroll 2
  for (int k = k0; k < kend; k += 2) {
    float w0 = W[(size_t)k * N + tid];
    float w1 = W[(size_t)(k + 1) * N + tid];
#pragma unroll
    for (int m = 0; m < 32; ++m) {
      float2 hp = *reinterpret_cast<const float2*>(h + (size_t)m * FLAT + k);
      acc[m] = fmaf(hp.x, w0, acc[m]);
      acc[m] = fmaf(hp.y, w1, acc[m]);
    }
  }
  float* out = partial + (size_t)blockIdx.x * CSTRIDE;
#pragma unroll
  for (int m = 0; m < 32; ++m) out[m * N + tid] = acc[m];
}

// ---------------- fused tail: reduce partials + both MLP branches + heads ---------
__global__ __launch_bounds__(256) void fused_tail(
    const float* __restrict__ part1, const float* __restrict__ part2,
    const float* __restrict__ b_c1, const float* __restrict__ w_c2,
    const float* __restrict__ b_c2, const float* __restrict__ w_co,
    const float* __restrict__ b_co, const float* __restrict__ w_sm,
    const float* __restrict__ b_sm, const float* __restrict__ b_r1,
    const float* __restrict__ w_r2, const float* __restrict__ b_r2,
    const float* __restrict__ w_r3, const float* __restrict__ b_r3,
    const float* __restrict__ w_r4, const float* __restrict__ b_r4,
    const float* __restrict__ w_ro, const float* __restrict__ b_ro,
    const float* __restrict__ w_sg, const float* __restrict__ b_sg,
    float* __restrict__ class_out, float* __restrict__ reg_out) {
  __shared__ float ly1[512], lz1[256], ly2[256], ly3[2928];
  __shared__ float lz2[128], lz3[128], lz4[64], lzo[900];
  int m = blockIdx.x, t = threadIdx.x;
  // phase 0: sum split-K partials + bias + leaky -> y1(512), z1(256)
  {
    float s0 = 0.f, s1 = 0.f, s2 = 0.f;
    const float* p0 = part1 + m * 512 + t;
    const float* p1 = p0 + 256;
    const float* p2 = part2 + m * 256 + t;
#pragma unroll 4
    for (int c = 0; c < NCHUNK; ++c) {
      s0 += p0[(size_t)c * PSTRIDE1];
      s1 += p1[(size_t)c * PSTRIDE1];
      s2 += p2[(size_t)c * PSTRIDE2];
    }
    s0 += b_c1[t]; s1 += b_c1[t + 256]; s2 += b_r1[t];
    ly1[t] = s0 > 0.f ? s0 : ALPHA * s0;
    ly1[t + 256] = s1 > 0.f ? s1 : ALPHA * s1;
    lz1[t] = s2 > 0.f ? s2 : ALPHA * s2;
  }
  __syncthreads();
  // phase 1: y2 (256 outs, K=512) and z2 (128 outs, K=256)
  {
    float s = b_c2[t];
    for (int k = 0; k < 512; ++k) s = fmaf(ly1[k], w_c2[k * 256 + t], s);
    ly2[t] = s > 0.f ? s : ALPHA * s;
  }
  if (t < 128) {
    float s = b_r2[t];
    for (int k = 0; k < 256; ++k) s = fmaf(lz1[k], w_r2[k * 128 + t], s);
    lz2[t] = s > 0.f ? s : ALPHA * s;
  }
  __syncthreads();
  // phase 2: y3 (2925 outs, K=256) and z3 (128 outs, K=128)
  for (int n = t; n < 2925; n += 256) {
    float s = b_co[n];
    for (int k = 0; k < 256; ++k) s = fmaf(ly2[k], w_co[k * 2925 + n], s);
    ly3[n] = s > 0.f ? s : ALPHA * s;
  }
  if (t < 128) {
    float s = b_r3[t];
    for (int k = 0; k < 128; ++k) s = fmaf(lz2[k], w_r3[k * 128 + t], s);
    lz3[t] = s > 0.f ? s : ALPHA * s;
  }
  __syncthreads();
  // phase 3: z4 (64 outs, K=128)
  if (t < 64) {
    float s = b_r4[t];
    for (int k = 0; k < 128; ++k) s = fmaf(lz3[k], w_r4[k * 64 + t], s);
    lz4[t] = s > 0.f ? s : ALPHA * s;
  }
  __syncthreads();
  // phase 4: zo (900 outs, K=64, no activation)
  for (int n = t; n < 900; n += 256) {
    float s = b_ro[n];
#pragma unroll
    for (int k = 0; k < 64; ++k) s = fmaf(lz4[k], w_ro[k * 900 + n], s);
    lzo[n] = s;
  }
  __syncthreads();
  // phase 5: heads (225 rows)
  if (t < 225) {
    float v[13], l[13], mx = -1e30f;
#pragma unroll
    for (int i = 0; i < 13; ++i) v[i] = ly3[t * 13 + i];
#pragma unroll
    for (int j = 0; j < 13; ++j) {
      float s = b_sm[j];
#pragma unroll
      for (int i = 0; i < 13; ++i) s = fmaf(v[i], w_sm[i * 13 + j], s);
      l[j] = s; mx = fmaxf(mx, s);
    }
    float sum = 0.f;
#pragma unroll
    for (int j = 0; j < 13; ++j) { l[j] = expf(l[j] - mx); sum += l[j]; }
    float inv = 1.f / sum;
    float* o = class_out + ((size_t)m * 225 + t) * 13;
#pragma unroll
    for (int j = 0; j < 13; ++j) o[j] = l[j] * inv;

    float z[4];
#pragma unroll
    for (int i = 0; i < 4; ++i) z[i] = lzo[t * 4 + i];
    float* ro = reg_out + ((size_t)m * 225 + t) * 4;
#pragma unroll
    for (int j = 0; j < 4; ++j) {
      float s = b_sg[j];
#pragma unroll
      for (int i = 0; i < 4; ++i) s = fmaf(z[i], w_sg[i * 4 + j], s);
      ro[j] = 1.f / (1.f + expf(-s));
    }
  }
}

// ---------------- workspace layout (bytes) ----------------
#define OFF_P1     ((size_t)0)            // 25,229,312
#define OFF_BPACK  ((size_t)25229312)     // 36,864
#define OFF_H      ((size_t)25266176)     // 23,871,488
#define OFF_PART1  ((size_t)49137664)     // 365*16448*4 = 24,014,080
#define OFF_PART2  ((size_t)73151744)     // 365*8256*4  = 12,053,760

extern "C" void kernel_launch(void* const* d_in, const int* in_sizes, int n_in,
                              void* d_out, int out_size, void* d_ws, size_t ws_size,
                              hipStream_t stream) {
  const float* x     = (const float*)d_in[0];
  const float* w1    = (const float*)d_in[1];
  const float* b1    = (const float*)d_in[2];
  const float* w2    = (const float*)d_in[3];
  const float* b2    = (const float*)d_in[4];
  const float* w_c1  = (const float*)d_in[5];
  const float* b_c1  = (const float*)d_in[6];
  const float* w_c2  = (const float*)d_in[7];
  const float* b_c2  = (const float*)d_in[8];
  const float* w_co  = (const float*)d_in[9];
  const float* b_co  = (const float*)d_in[10];
  const float* w_sm  = (const float*)d_in[11];
  const float* b_sm  = (const float*)d_in[12];
  const float* w_r1  = (const float*)d_in[13];
  const float* b_r1  = (const float*)d_in[14];
  const float* w_r2  = (const float*)d_in[15];
  const float* b_r2  = (const float*)d_in[16];
  const float* w_r3  = (const float*)d_in[17];
  const float* b_r3  = (const float*)d_in[18];
  const float* w_r4  = (const float*)d_in[19];
  const float* b_r4  = (const float*)d_in[20];
  const float* w_ro  = (const float*)d_in[21];
  const float* b_ro  = (const float*)d_in[22];
  const float* w_sg  = (const float*)d_in[23];
  const float* b_sg  = (const float*)d_in[24];

  char* ws = (char*)d_ws;
  unsigned short* p1    = (unsigned short*)(ws + OFF_P1);
  unsigned short* bpack = (unsigned short*)(ws + OFF_BPACK);
  float*          h     = (float*)(ws + OFF_H);
  float*          part1 = (float*)(ws + OFF_PART1);
  float*          part2 = (float*)(ws + OFF_PART2);

  float* class_out = (float*)d_out;
  float* reg_out   = (float*)d_out + 32 * 225 * 13;

  conv1_pool<<<1540, 256, 0, stream>>>(x, w1, b1, p1);
  repack_w2<<<72, 256, 0, stream>>>(w2, bpack);
  conv2_pool<<<dim3(47, 32), 256, 0, stream>>>(p1, bpack, b2, h);
  gemm_big<512, PSTRIDE1><<<NCHUNK, 512, 0, stream>>>(w_c1, h, part1);
  gemm_big<256, PSTRIDE2><<<NCHUNK, 256, 0, stream>>>(w_r1, h, part2);
  fused_tail<<<32, 256, 0, stream>>>(part1, part2,
      b_c1, w_c2, b_c2, w_co, b_co, w_sm, b_sm,
      b_r1, w_r2, b_r2, w_r3, b_r3, w_r4, b_r4,
      w_ro, b_ro, w_sg, b_sg, class_out, reg_out);
}

// Round 3
// 630.170 us; speedup vs baseline: 1.6845x; 1.6845x over previous
//
#include <hip/hip_runtime.h>
#include <hip/hip_bf16.h>

#define ALPHA 0.01f

typedef __attribute__((ext_vector_type(8))) __bf16 bf16x8;
typedef __attribute__((ext_vector_type(4))) float f32x4;

#define BATCH 32
#define P1H 97
#define P1W 127
#define P2W 62
#define FLAT 186496
#define CHUNK 512
#define NCHUNK 365            // ceil(186496/512)
#define PSTRIDE1 16448        // 32*512 + 64 pad (floats) — break pow-2 stride
#define PSTRIDE2 8256         // 32*256 + 64 pad

static __device__ __forceinline__ unsigned short f2bf(float x) {
  union { float f; unsigned u; } c; c.f = x;
  unsigned r = c.u + 0x7fffu + ((c.u >> 16) & 1u);
  return (unsigned short)(r >> 16);
}

// ---------------- conv1 (3x3x1->32) + ReLU + 2x2 maxpool, out bf16 ----------------
__global__ __launch_bounds__(256) void conv1_pool(const float* __restrict__ x,
    const float* __restrict__ w1, const float* __restrict__ b1,
    unsigned short* __restrict__ p1) {
  int pid = blockIdx.x * 256 + threadIdx.x;
  if (pid >= BATCH * P1H * P1W) return;
  int b = pid / (P1H * P1W);
  int rem = pid - b * (P1H * P1W);
  int ph = rem / P1W;
  int pw = rem - ph * P1W;
  const float* xb = x + ((b * 197 + 2 * ph) * 256 + 2 * pw);
  float in[4][4];
#pragma unroll
  for (int r = 0; r < 4; ++r) {
    float2 v0 = *reinterpret_cast<const float2*>(xb + r * 256);
    float2 v1 = *reinterpret_cast<const float2*>(xb + r * 256 + 2);
    in[r][0] = v0.x; in[r][1] = v0.y; in[r][2] = v1.x; in[r][3] = v1.y;
  }
  unsigned pk[16];
#pragma unroll
  for (int c = 0; c < 32; ++c) {
    float s00 = b1[c], s01 = s00, s10 = s00, s11 = s00;
#pragma unroll
    for (int ky = 0; ky < 3; ++ky)
#pragma unroll
      for (int kx = 0; kx < 3; ++kx) {
        float w = w1[(ky * 3 + kx) * 32 + c];
        s00 = fmaf(in[ky][kx], w, s00);
        s01 = fmaf(in[ky][kx + 1], w, s01);
        s10 = fmaf(in[ky + 1][kx], w, s10);
        s11 = fmaf(in[ky + 1][kx + 1], w, s11);
      }
    float m = fmaxf(fmaxf(s00, s01), fmaxf(s10, s11));
    m = fmaxf(m, 0.0f);
    unsigned short u = f2bf(m);
    if (c & 1) pk[c >> 1] |= ((unsigned)u) << 16;
    else pk[c >> 1] = (unsigned)u;
  }
  uint4* dst = reinterpret_cast<uint4*>(p1 + (size_t)pid * 32);
#pragma unroll
  for (int g = 0; g < 4; ++g)
    dst[g] = make_uint4(pk[g * 4], pk[g * 4 + 1], pk[g * 4 + 2], pk[g * 4 + 3]);
}

// ---------------- repack conv2 weights (3,3,32,64) f32 -> bf16 MFMA B-fragments ----
__global__ __launch_bounds__(256) void repack_w2(const float* __restrict__ w2,
                                                 unsigned short* __restrict__ bpack) {
  int o = blockIdx.x * 256 + threadIdx.x;
  if (o >= 9 * 4 * 512) return;
  int f = o >> 9;
  int within = o & 511;
  int lane = within >> 3, j = within & 7;
  int tap = f >> 2, nf = f & 3;
  int k = ((lane >> 4) << 3) + j;
  int n = nf * 16 + (lane & 15);
  bpack[o] = f2bf(w2[(tap * 32 + k) * 64 + n]);
}

// ---------------- conv2 (3x3x32->64) MFMA + bias + ReLU + 2x2 maxpool -> h f32 -----
__global__ __launch_bounds__(256) void conv2_pool(const unsigned short* __restrict__ p1,
    const unsigned short* __restrict__ bpack, const float* __restrict__ b2,
    float* __restrict__ h) {
  __shared__ alignas(16) unsigned char lds_buf[65536];
  int prow = blockIdx.x, b = blockIdx.y;
  int tid = threadIdx.x;
  int lane = tid & 63, wid = tid >> 6;
  {
    const uint4* src = reinterpret_cast<const uint4*>(bpack);
    uint4* dst = reinterpret_cast<uint4*>(lds_buf);
    for (int i = tid; i < 2304; i += 256) dst[i] = src[i];
  }
  __syncthreads();
  int row = lane & 15, kg = lane >> 4;
  int rowbase[4];
  int coff[4][3];
#pragma unroll
  for (int mf = 0; mf < 4; ++mf) {
    int m = wid * 64 + mf * 16 + row;
    int cro = m >> 7, cc = m & 127;
    rowbase[mf] = ((b * 97 + 2 * prow + cro) * 127) * 32 + kg * 8;
#pragma unroll
    for (int kx = 0; kx < 3; ++kx) {
      int ic = cc + kx; if (ic > 126) ic = 126;
      coff[mf][kx] = ic * 32;
    }
  }
  f32x4 acc[4][4];
#pragma unroll
  for (int i = 0; i < 4; ++i)
#pragma unroll
    for (int j = 0; j < 4; ++j) acc[i][j] = (f32x4){0.f, 0.f, 0.f, 0.f};

  const bf16x8* bl = reinterpret_cast<const bf16x8*>(lds_buf);
#pragma unroll
  for (int ky = 0; ky < 3; ++ky) {
#pragma unroll
    for (int kx = 0; kx < 3; ++kx) {
      int tap = ky * 3 + kx;
      bf16x8 a[4];
#pragma unroll
      for (int mf = 0; mf < 4; ++mf) {
        int addr = rowbase[mf] + ky * (127 * 32) + coff[mf][kx];
        a[mf] = *reinterpret_cast<const bf16x8*>(p1 + addr);
      }
      bf16x8 bf[4];
#pragma unroll
      for (int nf = 0; nf < 4; ++nf) bf[nf] = bl[(tap * 4 + nf) * 64 + lane];
#pragma unroll
      for (int nf = 0; nf < 4; ++nf)
#pragma unroll
        for (int mf = 0; mf < 4; ++mf)
          acc[mf][nf] = __builtin_amdgcn_mfma_f32_16x16x32_bf16(a[mf], bf[nf], acc[mf][nf], 0, 0, 0);
    }
  }
  __syncthreads();
  float* stage = reinterpret_cast<float*>(lds_buf);
#pragma unroll
  for (int mf = 0; mf < 4; ++mf)
#pragma unroll
    for (int nf = 0; nf < 4; ++nf) {
      int ch = nf * 16 + (lane & 15);
      float bias = b2[ch];
#pragma unroll
      for (int j = 0; j < 4; ++j) {
        int m = wid * 64 + mf * 16 + (lane >> 4) * 4 + j;
        float v = acc[mf][nf][j] + bias;
        stage[m * 64 + ch] = fmaxf(v, 0.f);
      }
    }
  __syncthreads();
  float* hb = h + (size_t)b * FLAT + prow * (P2W * 64);
  for (int o = tid; o < P2W * 64; o += 256) {
    int pw = o >> 6, ch = o & 63;
    int c0 = 2 * pw;
    float v = fmaxf(fmaxf(stage[c0 * 64 + ch], stage[(c0 + 1) * 64 + ch]),
                    fmaxf(stage[(128 + c0) * 64 + ch], stage[(129 + c0) * 64 + ch]));
    hb[o] = v;
  }
}

// ---------------- big skinny GEMM, h chunk staged in LDS ----------------
// N=512: 256 threads, float2 cols per thread
__global__ __launch_bounds__(256) void gemm_big512(const float* __restrict__ W,
    const float* __restrict__ h, float* __restrict__ partial) {
  __shared__ float lh[32][512];
  int t = threadIdx.x;
  int k0 = blockIdx.x * CHUNK;
  int klen = FLAT - k0; if (klen > CHUNK) klen = CHUNK;
#pragma unroll
  for (int i = 0; i < 16; ++i) {
    int l = t + i * 256;
    int m = l >> 7, kk = (l & 127) << 2;
    float4 v = *reinterpret_cast<const float4*>(h + (size_t)m * FLAT + k0 + kk);
    *reinterpret_cast<float4*>(&lh[m][kk]) = v;
  }
  __syncthreads();
  const float2* Wv = reinterpret_cast<const float2*>(W) + t;
  float2 acc[32];
#pragma unroll
  for (int m = 0; m < 32; ++m) acc[m] = make_float2(0.f, 0.f);
  for (int k = 0; k < klen; k += 2) {
    float2 w0 = Wv[(size_t)(k0 + k) * 256];
    float2 w1 = Wv[(size_t)(k0 + k + 1) * 256];
#pragma unroll
    for (int m = 0; m < 32; ++m) {
      float2 hm = *reinterpret_cast<const float2*>(&lh[m][k]);
      acc[m].x = fmaf(hm.x, w0.x, acc[m].x);
      acc[m].y = fmaf(hm.x, w0.y, acc[m].y);
      acc[m].x = fmaf(hm.y, w1.x, acc[m].x);
      acc[m].y = fmaf(hm.y, w1.y, acc[m].y);
    }
  }
  float* out = partial + (size_t)blockIdx.x * PSTRIDE1;
#pragma unroll
  for (int m = 0; m < 32; ++m)
    reinterpret_cast<float2*>(out + m * 512)[t] = acc[m];
}

// N=256: 256 threads, one col per thread
__global__ __launch_bounds__(256) void gemm_big256(const float* __restrict__ W,
    const float* __restrict__ h, float* __restrict__ partial) {
  __shared__ float lh[32][512];
  int t = threadIdx.x;
  int k0 = blockIdx.x * CHUNK;
  int klen = FLAT - k0; if (klen > CHUNK) klen = CHUNK;
#pragma unroll
  for (int i = 0; i < 16; ++i) {
    int l = t + i * 256;
    int m = l >> 7, kk = (l & 127) << 2;
    float4 v = *reinterpret_cast<const float4*>(h + (size_t)m * FLAT + k0 + kk);
    *reinterpret_cast<float4*>(&lh[m][kk]) = v;
  }
  __syncthreads();
  const float* Wp = W + t;
  float acc[32];
#pragma unroll
  for (int m = 0; m < 32; ++m) acc[m] = 0.f;
  for (int k = 0; k < klen; k += 2) {
    float w0 = Wp[(size_t)(k0 + k) * 256];
    float w1 = Wp[(size_t)(k0 + k + 1) * 256];
#pragma unroll
    for (int m = 0; m < 32; ++m) {
      float2 hm = *reinterpret_cast<const float2*>(&lh[m][k]);
      acc[m] = fmaf(hm.x, w0, acc[m]);
      acc[m] = fmaf(hm.y, w1, acc[m]);
    }
  }
  float* out = partial + (size_t)blockIdx.x * PSTRIDE2;
#pragma unroll
  for (int m = 0; m < 32; ++m) out[m * 256 + t] = acc[m];
}

// ---------------- reduce split-K partials: 768 blocks, 8 threads/output ----------
__global__ __launch_bounds__(256) void reduce_big(const float* __restrict__ part1,
    const float* __restrict__ part2, const float* __restrict__ b_c1,
    const float* __restrict__ b_r1, float* __restrict__ y1, float* __restrict__ z1) {
  __shared__ float red[8][32];
  int b = blockIdx.x, t = threadIdx.x;
  int oo = t & 31, j = t >> 5;
  float s = 0.f;
  if (b < 512) {
    const float* p = part1 + b * 32 + oo;
    for (int c = j; c < NCHUNK; c += 8) s += p[(size_t)c * PSTRIDE1];
    red[j][oo] = s;
    __syncthreads();
    if (t < 32) {
      float r = 0.f;
#pragma unroll
      for (int jj = 0; jj < 8; ++jj) r += red[jj][t];
      int o = b * 32 + t;
      r += b_c1[o & 511];
      y1[o] = r > 0.f ? r : ALPHA * r;
    }
  } else {
    const float* p = part2 + (b - 512) * 32 + oo;
    for (int c = j; c < NCHUNK; c += 8) s += p[(size_t)c * PSTRIDE2];
    red[j][oo] = s;
    __syncthreads();
    if (t < 32) {
      float r = 0.f;
#pragma unroll
      for (int jj = 0; jj < 8; ++jj) r += red[jj][t];
      int u = (b - 512) * 32 + t;
      r += b_r1[u & 255];
      z1[u] = r > 0.f ? r : ALPHA * r;
    }
  }
}

// ---------------- tail MLP: grid (32 m, 2 branches) ----------------
__global__ __launch_bounds__(256) void tail_mlp(
    const float* __restrict__ y1g, const float* __restrict__ z1g,
    const float* __restrict__ w_c2, const float* __restrict__ b_c2,
    const float* __restrict__ w_co, const float* __restrict__ b_co,
    const float* __restrict__ w_sm, const float* __restrict__ b_sm,
    const float* __restrict__ w_r2, const float* __restrict__ b_r2,
    const float* __restrict__ w_r3, const float* __restrict__ b_r3,
    const float* __restrict__ w_r4, const float* __restrict__ b_r4,
    const float* __restrict__ w_ro, const float* __restrict__ b_ro,
    const float* __restrict__ w_sg, const float* __restrict__ b_sg,
    float* __restrict__ class_out, float* __restrict__ reg_out) {
  int m = blockIdx.x, t = threadIdx.x;
  if (blockIdx.y == 0) {
    __shared__ float ly1[512], ly2[256], ly3[2925];
    ly1[t] = y1g[m * 512 + t];
    ly1[t + 256] = y1g[m * 512 + 256 + t];
    __syncthreads();
    {
      float s = b_c2[t];
      for (int k = 0; k < 512; ++k) s = fmaf(ly1[k], w_c2[k * 256 + t], s);
      ly2[t] = s > 0.f ? s : ALPHA * s;
    }
    __syncthreads();
    for (int n = t; n < 2925; n += 256) {
      float s = b_co[n];
      for (int k = 0; k < 256; ++k) s = fmaf(ly2[k], w_co[k * 2925 + n], s);
      ly3[n] = s > 0.f ? s : ALPHA * s;
    }
    __syncthreads();
    if (t < 225) {
      float v[13], l[13], mx = -1e30f;
#pragma unroll
      for (int i = 0; i < 13; ++i) v[i] = ly3[t * 13 + i];
#pragma unroll
      for (int j = 0; j < 13; ++j) {
        float s = b_sm[j];
#pragma unroll
        for (int i = 0; i < 13; ++i) s = fmaf(v[i], w_sm[i * 13 + j], s);
        l[j] = s; mx = fmaxf(mx, s);
      }
      float sum = 0.f;
#pragma unroll
      for (int j = 0; j < 13; ++j) { l[j] = expf(l[j] - mx); sum += l[j]; }
      float inv = 1.f / sum;
      float* o = class_out + ((size_t)m * 225 + t) * 13;
#pragma unroll
      for (int j = 0; j < 13; ++j) o[j] = l[j] * inv;
    }
  } else {
    __shared__ float lz1[256], lz2[128], lz3[128], lz4[64], lzo[900];
    lz1[t] = z1g[m * 256 + t];
    __syncthreads();
    if (t < 128) {
      float s = b_r2[t];
      for (int k = 0; k < 256; ++k) s = fmaf(lz1[k], w_r2[k * 128 + t], s);
      lz2[t] = s > 0.f ? s : ALPHA * s;
    }
    __syncthreads();
    if (t < 128) {
      float s = b_r3[t];
      for (int k = 0; k < 128; ++k) s = fmaf(lz2[k], w_r3[k * 128 + t], s);
      lz3[t] = s > 0.f ? s : ALPHA * s;
    }
    __syncthreads();
    if (t < 64) {
      float s = b_r4[t];
      for (int k = 0; k < 128; ++k) s = fmaf(lz3[k], w_r4[k * 64 + t], s);
      lz4[t] = s > 0.f ? s : ALPHA * s;
    }
    __syncthreads();
    for (int n = t; n < 900; n += 256) {
      float s = b_ro[n];
#pragma unroll
      for (int k = 0; k < 64; ++k) s = fmaf(lz4[k], w_ro[k * 900 + n], s);
      lzo[n] = s;
    }
    __syncthreads();
    if (t < 225) {
      float z[4];
#pragma unroll
      for (int i = 0; i < 4; ++i) z[i] = lzo[t * 4 + i];
      float* ro = reg_out + ((size_t)m * 225 + t) * 4;
#pragma unroll
      for (int j = 0; j < 4; ++j) {
        float s = b_sg[j];
#pragma unroll
        for (int i = 0; i < 4; ++i) s = fmaf(z[i], w_sg[i * 4 + j], s);
        ro[j] = 1.f / (1.f + expf(-s));
      }
    }
  }
}

// ---------------- workspace layout (bytes) ----------------
#define OFF_P1     ((size_t)0)            // 25,229,312
#define OFF_BPACK  ((size_t)25229312)     // 36,864
#define OFF_H      ((size_t)25266176)     // 23,871,488
#define OFF_PART1  ((size_t)49137664)     // 365*16448*4 = 24,014,080
#define OFF_PART2  ((size_t)73151744)     // 365*8256*4  = 12,053,760
#define OFF_Y1     ((size_t)85205504)     // 65,536
#define OFF_Z1     ((size_t)85271040)     // 32,768

extern "C" void kernel_launch(void* const* d_in, const int* in_sizes, int n_in,
                              void* d_out, int out_size, void* d_ws, size_t ws_size,
                              hipStream_t stream) {
  const float* x     = (const float*)d_in[0];
  const float* w1    = (const float*)d_in[1];
  const float* b1    = (const float*)d_in[2];
  const float* w2    = (const float*)d_in[3];
  const float* b2    = (const float*)d_in[4];
  const float* w_c1  = (const float*)d_in[5];
  const float* b_c1  = (const float*)d_in[6];
  const float* w_c2  = (const float*)d_in[7];
  const float* b_c2  = (const float*)d_in[8];
  const float* w_co  = (const float*)d_in[9];
  const float* b_co  = (const float*)d_in[10];
  const float* w_sm  = (const float*)d_in[11];
  const float* b_sm  = (const float*)d_in[12];
  const float* w_r1  = (const float*)d_in[13];
  const float* b_r1  = (const float*)d_in[14];
  const float* w_r2  = (const float*)d_in[15];
  const float* b_r2  = (const float*)d_in[16];
  const float* w_r3  = (const float*)d_in[17];
  const float* b_r3  = (const float*)d_in[18];
  const float* w_r4  = (const float*)d_in[19];
  const float* b_r4  = (const float*)d_in[20];
  const float* w_ro  = (const float*)d_in[21];
  const float* b_ro  = (const float*)d_in[22];
  const float* w_sg  = (const float*)d_in[23];
  const float* b_sg  = (const float*)d_in[24];

  char* ws = (char*)d_ws;
  unsigned short* p1    = (unsigned short*)(ws + OFF_P1);
  unsigned short* bpack = (unsigned short*)(ws + OFF_BPACK);
  float*          h     = (float*)(ws + OFF_H);
  float*          part1 = (float*)(ws + OFF_PART1);
  float*          part2 = (float*)(ws + OFF_PART2);
  float*          y1    = (float*)(ws + OFF_Y1);
  float*          z1    = (float*)(ws + OFF_Z1);

  float* class_out = (float*)d_out;
  float* reg_out   = (float*)d_out + 32 * 225 * 13;

  conv1_pool<<<1540, 256, 0, stream>>>(x, w1, b1, p1);
  repack_w2<<<72, 256, 0, stream>>>(w2, bpack);
  conv2_pool<<<dim3(47, 32), 256, 0, stream>>>(p1, bpack, b2, h);
  gemm_big512<<<NCHUNK, 256, 0, stream>>>(w_c1, h, part1);
  gemm_big256<<<NCHUNK, 256, 0, stream>>>(w_r1, h, part2);
  reduce_big<<<768, 256, 0, stream>>>(part1, part2, b_c1, b_r1, y1, z1);
  tail_mlp<<<dim3(32, 2), 256, 0, stream>>>(y1, z1,
      w_c2, b_c2, w_co, b_co, w_sm, b_sm,
      w_r2, b_r2, w_r3, b_r3, w_r4, b_r4,
      w_ro, b_ro, w_sg, b_sg, class_out, reg_out);
}

// Round 4
// 475.258 us; speedup vs baseline: 2.2335x; 1.3260x over previous
//
#include <hip/hip_runtime.h>
#include <hip/hip_bf16.h>

#define ALPHA 0.01f

typedef __attribute__((ext_vector_type(8))) __bf16 bf16x8;
typedef __attribute__((ext_vector_type(4))) float f32x4;

#define BATCH 32
#define P1H 97
#define P1W 127
#define P2W 62
#define FLAT 186496
#define CHUNK 512
#define NCHUNK 365            // ceil(186496/512)
#define PSTRIDE1 16448        // 32*512 + 64 pad (floats) — break pow-2 stride
#define PSTRIDE2 8256         // 32*256 + 64 pad

static __device__ __forceinline__ unsigned short f2bf(float x) {
  union { float f; unsigned u; } c; c.f = x;
  unsigned r = c.u + 0x7fffu + ((c.u >> 16) & 1u);
  return (unsigned short)(r >> 16);
}

// ---------------- conv1 (3x3x1->32) + ReLU + 2x2 maxpool, out bf16 ----------------
__global__ __launch_bounds__(256) void conv1_pool(const float* __restrict__ x,
    const float* __restrict__ w1, const float* __restrict__ b1,
    unsigned short* __restrict__ p1) {
  int pid = blockIdx.x * 256 + threadIdx.x;
  if (pid >= BATCH * P1H * P1W) return;
  int b = pid / (P1H * P1W);
  int rem = pid - b * (P1H * P1W);
  int ph = rem / P1W;
  int pw = rem - ph * P1W;
  const float* xb = x + ((b * 197 + 2 * ph) * 256 + 2 * pw);
  float in[4][4];
#pragma unroll
  for (int r = 0; r < 4; ++r) {
    float2 v0 = *reinterpret_cast<const float2*>(xb + r * 256);
    float2 v1 = *reinterpret_cast<const float2*>(xb + r * 256 + 2);
    in[r][0] = v0.x; in[r][1] = v0.y; in[r][2] = v1.x; in[r][3] = v1.y;
  }
  unsigned pk[16];
#pragma unroll
  for (int c = 0; c < 32; ++c) {
    float s00 = b1[c], s01 = s00, s10 = s00, s11 = s00;
#pragma unroll
    for (int ky = 0; ky < 3; ++ky)
#pragma unroll
      for (int kx = 0; kx < 3; ++kx) {
        float w = w1[(ky * 3 + kx) * 32 + c];
        s00 = fmaf(in[ky][kx], w, s00);
        s01 = fmaf(in[ky][kx + 1], w, s01);
        s10 = fmaf(in[ky + 1][kx], w, s10);
        s11 = fmaf(in[ky + 1][kx + 1], w, s11);
      }
    float m = fmaxf(fmaxf(s00, s01), fmaxf(s10, s11));
    m = fmaxf(m, 0.0f);
    unsigned short u = f2bf(m);
    if (c & 1) pk[c >> 1] |= ((unsigned)u) << 16;
    else pk[c >> 1] = (unsigned)u;
  }
  uint4* dst = reinterpret_cast<uint4*>(p1 + (size_t)pid * 32);
#pragma unroll
  for (int g = 0; g < 4; ++g)
    dst[g] = make_uint4(pk[g * 4], pk[g * 4 + 1], pk[g * 4 + 2], pk[g * 4 + 3]);
}

// ---------------- repack conv2 weights (3,3,32,64) f32 -> bf16 MFMA B-fragments ----
__global__ __launch_bounds__(256) void repack_w2(const float* __restrict__ w2,
                                                 unsigned short* __restrict__ bpack) {
  int o = blockIdx.x * 256 + threadIdx.x;
  if (o >= 9 * 4 * 512) return;
  int f = o >> 9;
  int within = o & 511;
  int lane = within >> 3, j = within & 7;
  int tap = f >> 2, nf = f & 3;
  int k = ((lane >> 4) << 3) + j;
  int n = nf * 16 + (lane & 15);
  bpack[o] = f2bf(w2[(tap * 32 + k) * 64 + n]);
}

// ---------------- conv2 (3x3x32->64) MFMA + bias + ReLU + 2x2 maxpool -> h f32 -----
__global__ __launch_bounds__(256) void conv2_pool(const unsigned short* __restrict__ p1,
    const unsigned short* __restrict__ bpack, const float* __restrict__ b2,
    float* __restrict__ h) {
  __shared__ alignas(16) unsigned char lds_buf[65536];
  int prow = blockIdx.x, b = blockIdx.y;
  int tid = threadIdx.x;
  int lane = tid & 63, wid = tid >> 6;
  {
    const uint4* src = reinterpret_cast<const uint4*>(bpack);
    uint4* dst = reinterpret_cast<uint4*>(lds_buf);
    for (int i = tid; i < 2304; i += 256) dst[i] = src[i];
  }
  __syncthreads();
  int row = lane & 15, kg = lane >> 4;
  int rowbase[4];
  int coff[4][3];
#pragma unroll
  for (int mf = 0; mf < 4; ++mf) {
    int m = wid * 64 + mf * 16 + row;
    int cro = m >> 7, cc = m & 127;
    rowbase[mf] = ((b * 97 + 2 * prow + cro) * 127) * 32 + kg * 8;
#pragma unroll
    for (int kx = 0; kx < 3; ++kx) {
      int ic = cc + kx; if (ic > 126) ic = 126;
      coff[mf][kx] = ic * 32;
    }
  }
  f32x4 acc[4][4];
#pragma unroll
  for (int i = 0; i < 4; ++i)
#pragma unroll
    for (int j = 0; j < 4; ++j) acc[i][j] = (f32x4){0.f, 0.f, 0.f, 0.f};

  const bf16x8* bl = reinterpret_cast<const bf16x8*>(lds_buf);
#pragma unroll
  for (int ky = 0; ky < 3; ++ky) {
#pragma unroll
    for (int kx = 0; kx < 3; ++kx) {
      int tap = ky * 3 + kx;
      bf16x8 a[4];
#pragma unroll
      for (int mf = 0; mf < 4; ++mf) {
        int addr = rowbase[mf] + ky * (127 * 32) + coff[mf][kx];
        a[mf] = *reinterpret_cast<const bf16x8*>(p1 + addr);
      }
      bf16x8 bf[4];
#pragma unroll
      for (int nf = 0; nf < 4; ++nf) bf[nf] = bl[(tap * 4 + nf) * 64 + lane];
#pragma unroll
      for (int nf = 0; nf < 4; ++nf)
#pragma unroll
        for (int mf = 0; mf < 4; ++mf)
          acc[mf][nf] = __builtin_amdgcn_mfma_f32_16x16x32_bf16(a[mf], bf[nf], acc[mf][nf], 0, 0, 0);
    }
  }
  __syncthreads();
  float* stage = reinterpret_cast<float*>(lds_buf);
#pragma unroll
  for (int mf = 0; mf < 4; ++mf)
#pragma unroll
    for (int nf = 0; nf < 4; ++nf) {
      int ch = nf * 16 + (lane & 15);
      float bias = b2[ch];
#pragma unroll
      for (int j = 0; j < 4; ++j) {
        int m = wid * 64 + mf * 16 + (lane >> 4) * 4 + j;
        float v = acc[mf][nf][j] + bias;
        stage[m * 64 + ch] = fmaxf(v, 0.f);
      }
    }
  __syncthreads();
  float* hb = h + (size_t)b * FLAT + prow * (P2W * 64);
  for (int o = tid; o < P2W * 64; o += 256) {
    int pw = o >> 6, ch = o & 63;
    int c0 = 2 * pw;
    float v = fmaxf(fmaxf(stage[c0 * 64 + ch], stage[(c0 + 1) * 64 + ch]),
                    fmaxf(stage[(128 + c0) * 64 + ch], stage[(129 + c0) * 64 + ch]));
    hb[o] = v;
  }
}

// ---------------- merged big skinny GEMM: stage h once, both weight mats ----------
// waves 0-3 (t<256): w_c1 cols (float2 each), waves 4-5 (t>=256): w_r1 cols
__global__ __launch_bounds__(384) void gemm_both(const float* __restrict__ W1,
    const float* __restrict__ W2, const float* __restrict__ h,
    float* __restrict__ part1, float* __restrict__ part2) {
  __shared__ float lh[32][512];
  int t = threadIdx.x;
  int k0 = blockIdx.x * CHUNK;
  int klen = FLAT - k0; if (klen > CHUNK) klen = CHUNK;
  for (int l = t; l < 4096; l += 384) {
    int m = l >> 7, kk = (l & 127) << 2;
    *reinterpret_cast<float4*>(&lh[m][kk]) =
        *reinterpret_cast<const float4*>(h + (size_t)m * FLAT + k0 + kk);
  }
  __syncthreads();
  const float2* Wv;
  size_t stride;
  if (t < 256) { Wv = reinterpret_cast<const float2*>(W1) + t; stride = 256; }
  else         { Wv = reinterpret_cast<const float2*>(W2) + (t - 256); stride = 128; }
  float2 acc[32];
#pragma unroll
  for (int m = 0; m < 32; ++m) acc[m] = make_float2(0.f, 0.f);
  for (int k = 0; k < klen; k += 2) {
    float2 w0 = Wv[(size_t)(k0 + k) * stride];
    float2 w1 = Wv[(size_t)(k0 + k + 1) * stride];
#pragma unroll
    for (int m = 0; m < 32; ++m) {
      float2 hm = *reinterpret_cast<const float2*>(&lh[m][k]);
      acc[m].x = fmaf(hm.x, w0.x, acc[m].x);
      acc[m].y = fmaf(hm.x, w0.y, acc[m].y);
      acc[m].x = fmaf(hm.y, w1.x, acc[m].x);
      acc[m].y = fmaf(hm.y, w1.y, acc[m].y);
    }
  }
  if (t < 256) {
    float* out = part1 + (size_t)blockIdx.x * PSTRIDE1;
#pragma unroll
    for (int m = 0; m < 32; ++m)
      reinterpret_cast<float2*>(out + m * 512)[t] = acc[m];
  } else {
    float* out = part2 + (size_t)blockIdx.x * PSTRIDE2;
#pragma unroll
    for (int m = 0; m < 32; ++m)
      reinterpret_cast<float2*>(out + m * 256)[t - 256] = acc[m];
  }
}

// ---------------- reduce split-K partials: 768 blocks, 8 threads/output ----------
__global__ __launch_bounds__(256) void reduce_big(const float* __restrict__ part1,
    const float* __restrict__ part2, const float* __restrict__ b_c1,
    const float* __restrict__ b_r1, float* __restrict__ y1, float* __restrict__ z1) {
  __shared__ float red[8][32];
  int b = blockIdx.x, t = threadIdx.x;
  int oo = t & 31, j = t >> 5;
  float s = 0.f;
  if (b < 512) {
    const float* p = part1 + b * 32 + oo;
    for (int c = j; c < NCHUNK; c += 8) s += p[(size_t)c * PSTRIDE1];
    red[j][oo] = s;
    __syncthreads();
    if (t < 32) {
      float r = 0.f;
#pragma unroll
      for (int jj = 0; jj < 8; ++jj) r += red[jj][t];
      int o = b * 32 + t;
      r += b_c1[o & 511];
      y1[o] = r > 0.f ? r : ALPHA * r;
    }
  } else {
    const float* p = part2 + (b - 512) * 32 + oo;
    for (int c = j; c < NCHUNK; c += 8) s += p[(size_t)c * PSTRIDE2];
    red[j][oo] = s;
    __syncthreads();
    if (t < 32) {
      float r = 0.f;
#pragma unroll
      for (int jj = 0; jj < 8; ++jj) r += red[jj][t];
      int u = (b - 512) * 32 + t;
      r += b_r1[u & 255];
      z1[u] = r > 0.f ? r : ALPHA * r;
    }
  }
}

// ---------------- fully-parallel tail: grid (12 tiles, 32 m) ----------------------
// tiles 0-7: class branch, 29 positions each (last 22)
// tiles 8-11: regression branch, 57 positions each (last 54)
__global__ __launch_bounds__(256) void tail_all(
    const float* __restrict__ y1g, const float* __restrict__ z1g,
    const float* __restrict__ w_c2, const float* __restrict__ b_c2,
    const float* __restrict__ w_co, const float* __restrict__ b_co,
    const float* __restrict__ w_sm, const float* __restrict__ b_sm,
    const float* __restrict__ w_r2, const float* __restrict__ b_r2,
    const float* __restrict__ w_r3, const float* __restrict__ b_r3,
    const float* __restrict__ w_r4, const float* __restrict__ b_r4,
    const float* __restrict__ w_ro, const float* __restrict__ b_ro,
    const float* __restrict__ w_sg, const float* __restrict__ b_sg,
    float* __restrict__ class_out, float* __restrict__ reg_out) {
  int tile = blockIdx.x, m = blockIdx.y, t = threadIdx.x;
  if (tile < 8) {
    __shared__ float ly1[512], ly2[256], ly3[29 * 13];
    ly1[t] = y1g[m * 512 + t];
    ly1[t + 256] = y1g[m * 512 + 256 + t];
    __syncthreads();
    {
      float s = b_c2[t];
      for (int k = 0; k < 512; ++k) s = fmaf(ly1[k], w_c2[k * 256 + t], s);
      ly2[t] = s > 0.f ? s : ALPHA * s;
    }
    __syncthreads();
    int p0 = tile * 29;
    int np = 225 - p0; if (np > 29) np = 29;
    int ncols = np * 13;
    for (int n = t; n < ncols; n += 256) {
      int col = p0 * 13 + n;
      float s = b_co[col];
      for (int k = 0; k < 256; ++k) s = fmaf(ly2[k], w_co[k * 2925 + col], s);
      ly3[n] = s > 0.f ? s : ALPHA * s;
    }
    __syncthreads();
    if (t < np) {
      float v[13], l[13], mx = -1e30f;
#pragma unroll
      for (int i = 0; i < 13; ++i) v[i] = ly3[t * 13 + i];
#pragma unroll
      for (int j = 0; j < 13; ++j) {
        float s = b_sm[j];
#pragma unroll
        for (int i = 0; i < 13; ++i) s = fmaf(v[i], w_sm[i * 13 + j], s);
        l[j] = s; mx = fmaxf(mx, s);
      }
      float sum = 0.f;
#pragma unroll
      for (int j = 0; j < 13; ++j) { l[j] = expf(l[j] - mx); sum += l[j]; }
      float inv = 1.f / sum;
      float* o = class_out + ((size_t)m * 225 + p0 + t) * 13;
#pragma unroll
      for (int j = 0; j < 13; ++j) o[j] = l[j] * inv;
    }
  } else {
    __shared__ float lz1[256], lz2[128], lz3[128], lz4[64], lzo[57 * 4];
    lz1[t] = z1g[m * 256 + t];
    __syncthreads();
    if (t < 128) {
      float s = b_r2[t];
      for (int k = 0; k < 256; ++k) s = fmaf(lz1[k], w_r2[k * 128 + t], s);
      lz2[t] = s > 0.f ? s : ALPHA * s;
    }
    __syncthreads();
    if (t < 128) {
      float s = b_r3[t];
      for (int k = 0; k < 128; ++k) s = fmaf(lz2[k], w_r3[k * 128 + t], s);
      lz3[t] = s > 0.f ? s : ALPHA * s;
    }
    __syncthreads();
    if (t < 64) {
      float s = b_r4[t];
      for (int k = 0; k < 128; ++k) s = fmaf(lz3[k], w_r4[k * 64 + t], s);
      lz4[t] = s > 0.f ? s : ALPHA * s;
    }
    __syncthreads();
    int p0 = (tile - 8) * 57;
    int np = 225 - p0; if (np > 57) np = 57;
    int ncols = np * 4;
    for (int n = t; n < ncols; n += 256) {
      int col = p0 * 4 + n;
      float s = b_ro[col];
#pragma unroll
      for (int k = 0; k < 64; ++k) s = fmaf(lz4[k], w_ro[k * 900 + col], s);
      lzo[n] = s;
    }
    __syncthreads();
    if (t < np) {
      float z[4];
#pragma unroll
      for (int i = 0; i < 4; ++i) z[i] = lzo[t * 4 + i];
      float* ro = reg_out + ((size_t)m * 225 + p0 + t) * 4;
#pragma unroll
      for (int j = 0; j < 4; ++j) {
        float s = b_sg[j];
#pragma unroll
        for (int i = 0; i < 4; ++i) s = fmaf(z[i], w_sg[i * 4 + j], s);
        ro[j] = 1.f / (1.f + expf(-s));
      }
    }
  }
}

// ---------------- workspace layout (bytes) ----------------
#define OFF_P1     ((size_t)0)            // 25,229,312
#define OFF_BPACK  ((size_t)25229312)     // 36,864
#define OFF_H      ((size_t)25266176)     // 23,871,488
#define OFF_PART1  ((size_t)49137664)     // 365*16448*4 = 24,014,080
#define OFF_PART2  ((size_t)73151744)     // 365*8256*4  = 12,053,760
#define OFF_Y1     ((size_t)85205504)     // 65,536
#define OFF_Z1     ((size_t)85271040)     // 32,768

extern "C" void kernel_launch(void* const* d_in, const int* in_sizes, int n_in,
                              void* d_out, int out_size, void* d_ws, size_t ws_size,
                              hipStream_t stream) {
  const float* x     = (const float*)d_in[0];
  const float* w1    = (const float*)d_in[1];
  const float* b1    = (const float*)d_in[2];
  const float* w2    = (const float*)d_in[3];
  const float* b2    = (const float*)d_in[4];
  const float* w_c1  = (const float*)d_in[5];
  const float* b_c1  = (const float*)d_in[6];
  const float* w_c2  = (const float*)d_in[7];
  const float* b_c2  = (const float*)d_in[8];
  const float* w_co  = (const float*)d_in[9];
  const float* b_co  = (const float*)d_in[10];
  const float* w_sm  = (const float*)d_in[11];
  const float* b_sm  = (const float*)d_in[12];
  const float* w_r1  = (const float*)d_in[13];
  const float* b_r1  = (const float*)d_in[14];
  const float* w_r2  = (const float*)d_in[15];
  const float* b_r2  = (const float*)d_in[16];
  const float* w_r3  = (const float*)d_in[17];
  const float* b_r3  = (const float*)d_in[18];
  const float* w_r4  = (const float*)d_in[19];
  const float* b_r4  = (const float*)d_in[20];
  const float* w_ro  = (const float*)d_in[21];
  const float* b_ro  = (const float*)d_in[22];
  const float* w_sg  = (const float*)d_in[23];
  const float* b_sg  = (const float*)d_in[24];

  char* ws = (char*)d_ws;
  unsigned short* p1    = (unsigned short*)(ws + OFF_P1);
  unsigned short* bpack = (unsigned short*)(ws + OFF_BPACK);
  float*          h     = (float*)(ws + OFF_H);
  float*          part1 = (float*)(ws + OFF_PART1);
  float*          part2 = (float*)(ws + OFF_PART2);
  float*          y1    = (float*)(ws + OFF_Y1);
  float*          z1    = (float*)(ws + OFF_Z1);

  float* class_out = (float*)d_out;
  float* reg_out   = (float*)d_out + 32 * 225 * 13;

  conv1_pool<<<1540, 256, 0, stream>>>(x, w1, b1, p1);
  repack_w2<<<72, 256, 0, stream>>>(w2, bpack);
  conv2_pool<<<dim3(47, 32), 256, 0, stream>>>(p1, bpack, b2, h);
  gemm_both<<<NCHUNK, 384, 0, stream>>>(w_c1, w_r1, h, part1, part2);
  reduce_big<<<768, 256, 0, stream>>>(part1, part2, b_c1, b_r1, y1, z1);
  tail_all<<<dim3(12, 32), 256, 0, stream>>>(y1, z1,
      w_c2, b_c2, w_co, b_co, w_sm, b_sm,
      w_r2, b_r2, w_r3, b_r3, w_r4, b_r4,
      w_ro, b_ro, w_sg, b_sg, class_out, reg_out);
}

// Round 5
// 261.112 us; speedup vs baseline: 4.0653x; 1.8201x over previous
//
#include <hip/hip_runtime.h>
#include <hip/hip_bf16.h>

#define ALPHA 0.01f

typedef __attribute__((ext_vector_type(8))) __bf16 bf16x8;
typedef __attribute__((ext_vector_type(4))) float f32x4;

#define BATCH 32
#define P1H 97
#define P1W 127
#define P2W 62
#define FLAT 186496
#define GK 768
#define NGK 243               // ceil(186496/768); last chunk = 640 (20 k-steps)
#define PSTRIDE1 16448        // 32*512 + 64 pad (floats)
#define PSTRIDE2 8256         // 32*256 + 64 pad

static __device__ __forceinline__ unsigned short f2bf(float x) {
  union { float f; unsigned u; } c; c.f = x;
  unsigned r = c.u + 0x7fffu + ((c.u >> 16) & 1u);
  return (unsigned short)(r >> 16);
}

// ---------------- conv1 (3x3x1->32) + ReLU + 2x2 maxpool, out bf16 ----------------
__global__ __launch_bounds__(256) void conv1_pool(const float* __restrict__ x,
    const float* __restrict__ w1, const float* __restrict__ b1,
    unsigned short* __restrict__ p1) {
  int pid = blockIdx.x * 256 + threadIdx.x;
  if (pid >= BATCH * P1H * P1W) return;
  int b = pid / (P1H * P1W);
  int rem = pid - b * (P1H * P1W);
  int ph = rem / P1W;
  int pw = rem - ph * P1W;
  const float* xb = x + ((b * 197 + 2 * ph) * 256 + 2 * pw);
  float in[4][4];
#pragma unroll
  for (int r = 0; r < 4; ++r) {
    float2 v0 = *reinterpret_cast<const float2*>(xb + r * 256);
    float2 v1 = *reinterpret_cast<const float2*>(xb + r * 256 + 2);
    in[r][0] = v0.x; in[r][1] = v0.y; in[r][2] = v1.x; in[r][3] = v1.y;
  }
  unsigned pk[16];
#pragma unroll
  for (int c = 0; c < 32; ++c) {
    float s00 = b1[c], s01 = s00, s10 = s00, s11 = s00;
#pragma unroll
    for (int ky = 0; ky < 3; ++ky)
#pragma unroll
      for (int kx = 0; kx < 3; ++kx) {
        float w = w1[(ky * 3 + kx) * 32 + c];
        s00 = fmaf(in[ky][kx], w, s00);
        s01 = fmaf(in[ky][kx + 1], w, s01);
        s10 = fmaf(in[ky + 1][kx], w, s10);
        s11 = fmaf(in[ky + 1][kx + 1], w, s11);
      }
    float m = fmaxf(fmaxf(s00, s01), fmaxf(s10, s11));
    m = fmaxf(m, 0.0f);
    unsigned short u = f2bf(m);
    if (c & 1) pk[c >> 1] |= ((unsigned)u) << 16;
    else pk[c >> 1] = (unsigned)u;
  }
  uint4* dst = reinterpret_cast<uint4*>(p1 + (size_t)pid * 32);
#pragma unroll
  for (int g = 0; g < 4; ++g)
    dst[g] = make_uint4(pk[g * 4], pk[g * 4 + 1], pk[g * 4 + 2], pk[g * 4 + 3]);
}

// ---------------- repack conv2 weights (3,3,32,64) f32 -> bf16 MFMA B-fragments ----
__global__ __launch_bounds__(256) void repack_w2(const float* __restrict__ w2,
                                                 unsigned short* __restrict__ bpack) {
  int o = blockIdx.x * 256 + threadIdx.x;
  if (o >= 9 * 4 * 512) return;
  int f = o >> 9;
  int within = o & 511;
  int lane = within >> 3, j = within & 7;
  int tap = f >> 2, nf = f & 3;
  int k = ((lane >> 4) << 3) + j;
  int n = nf * 16 + (lane & 15);
  bpack[o] = f2bf(w2[(tap * 32 + k) * 64 + n]);
}

// ---------------- conv2 (3x3x32->64) MFMA + bias + ReLU + 2x2 maxpool -> h bf16 ----
__global__ __launch_bounds__(256) void conv2_pool(const unsigned short* __restrict__ p1,
    const unsigned short* __restrict__ bpack, const float* __restrict__ b2,
    unsigned short* __restrict__ hbf) {
  __shared__ alignas(16) unsigned char lds_buf[65536];
  int prow = blockIdx.x, b = blockIdx.y;
  int tid = threadIdx.x;
  int lane = tid & 63, wid = tid >> 6;
  {
    const uint4* src = reinterpret_cast<const uint4*>(bpack);
    uint4* dst = reinterpret_cast<uint4*>(lds_buf);
    for (int i = tid; i < 2304; i += 256) dst[i] = src[i];
  }
  __syncthreads();
  int row = lane & 15, kg = lane >> 4;
  int rowbase[4];
  int coff[4][3];
#pragma unroll
  for (int mf = 0; mf < 4; ++mf) {
    int m = wid * 64 + mf * 16 + row;
    int cro = m >> 7, cc = m & 127;
    rowbase[mf] = ((b * 97 + 2 * prow + cro) * 127) * 32 + kg * 8;
#pragma unroll
    for (int kx = 0; kx < 3; ++kx) {
      int ic = cc + kx; if (ic > 126) ic = 126;
      coff[mf][kx] = ic * 32;
    }
  }
  f32x4 acc[4][4];
#pragma unroll
  for (int i = 0; i < 4; ++i)
#pragma unroll
    for (int j = 0; j < 4; ++j) acc[i][j] = (f32x4){0.f, 0.f, 0.f, 0.f};

  const bf16x8* bl = reinterpret_cast<const bf16x8*>(lds_buf);
#pragma unroll
  for (int ky = 0; ky < 3; ++ky) {
#pragma unroll
    for (int kx = 0; kx < 3; ++kx) {
      int tap = ky * 3 + kx;
      bf16x8 a[4];
#pragma unroll
      for (int mf = 0; mf < 4; ++mf) {
        int addr = rowbase[mf] + ky * (127 * 32) + coff[mf][kx];
        a[mf] = *reinterpret_cast<const bf16x8*>(p1 + addr);
      }
      bf16x8 bf[4];
#pragma unroll
      for (int nf = 0; nf < 4; ++nf) bf[nf] = bl[(tap * 4 + nf) * 64 + lane];
#pragma unroll
      for (int nf = 0; nf < 4; ++nf)
#pragma unroll
        for (int mf = 0; mf < 4; ++mf)
          acc[mf][nf] = __builtin_amdgcn_mfma_f32_16x16x32_bf16(a[mf], bf[nf], acc[mf][nf], 0, 0, 0);
    }
  }
  __syncthreads();
  float* stage = reinterpret_cast<float*>(lds_buf);
#pragma unroll
  for (int mf = 0; mf < 4; ++mf)
#pragma unroll
    for (int nf = 0; nf < 4; ++nf) {
      int ch = nf * 16 + (lane & 15);
      float bias = b2[ch];
#pragma unroll
      for (int j = 0; j < 4; ++j) {
        int m = wid * 64 + mf * 16 + (lane >> 4) * 4 + j;
        float v = acc[mf][nf][j] + bias;
        stage[m * 64 + ch] = fmaxf(v, 0.f);
      }
    }
  __syncthreads();
  unsigned short* hb = hbf + (size_t)b * FLAT + prow * (P2W * 64);
  for (int o = tid; o < P2W * 64; o += 256) {
    int pw = o >> 6, ch = o & 63;
    int c0 = 2 * pw;
    float v = fmaxf(fmaxf(stage[c0 * 64 + ch], stage[(c0 + 1) * 64 + ch]),
                    fmaxf(stage[(128 + c0) * 64 + ch], stage[(129 + c0) * 64 + ch]));
    hb[o] = f2bf(v);
  }
}

// ---------------- MFMA big GEMM: h(32 x FLAT,bf16) @ [w_c1 | w_r1] ----------------
// grid (NGK k-chunks, 3 n-tiles). tiles 0,1 -> w_c1 cols 0..255 / 256..511 (part1)
// tile 2 -> w_r1 (part2). 512 threads = 8 waves; wave wid covers n-frags wid*2,+1.
// B-frags gathered per-lane from global f32 W + RNE cvt to bf16 (no LDS, no barriers).
__global__ __launch_bounds__(512) void gemm_mfma(
    const float* __restrict__ w_c1, const float* __restrict__ w_r1,
    const unsigned short* __restrict__ hbf,
    float* __restrict__ part1, float* __restrict__ part2) {
  int kc = blockIdx.x, tile = blockIdx.y;
  int t = threadIdx.x, lane = t & 63, wid = t >> 6;
  int k0 = kc * GK;
  int klen = FLAT - k0; if (klen > GK) klen = GK;
  int nsteps = klen >> 5;
  const float* W; int N, n0;
  if (tile < 2) { W = w_c1; N = 512; n0 = tile * 256; }
  else          { W = w_r1; N = 256; n0 = 0; }
  int cl = lane & 15, kg = lane >> 4;
  // per-lane W gather base (column n0+wid*32+cl, k-row k0+kg*8)
  const float* Wb0 = W + (size_t)(k0 + kg * 8) * N + (n0 + wid * 32 + cl);
  const float* Wb1 = Wb0 + 16;
  const unsigned short* ha = hbf + (size_t)cl * FLAT + k0 + kg * 8;

  f32x4 acc[2][2];
#pragma unroll
  for (int i = 0; i < 2; ++i)
#pragma unroll
    for (int j = 0; j < 2; ++j) acc[i][j] = (f32x4){0.f, 0.f, 0.f, 0.f};

#pragma unroll 2
  for (int s = 0; s < nsteps; ++s) {
    bf16x8 a0 = *reinterpret_cast<const bf16x8*>(ha + s * 32);
    bf16x8 a1 = *reinterpret_cast<const bf16x8*>(ha + (size_t)16 * FLAT + s * 32);
    const float* wp0 = Wb0 + (size_t)s * 32 * N;
    const float* wp1 = Wb1 + (size_t)s * 32 * N;
    float e0[8], e1[8];
#pragma unroll
    for (int j = 0; j < 8; ++j) {
      e0[j] = wp0[(size_t)j * N];
      e1[j] = wp1[(size_t)j * N];
    }
    union { unsigned u[4]; bf16x8 v; } b0, b1;
#pragma unroll
    for (int p = 0; p < 4; ++p) {
      b0.u[p] = (unsigned)f2bf(e0[2 * p]) | ((unsigned)f2bf(e0[2 * p + 1]) << 16);
      b1.u[p] = (unsigned)f2bf(e1[2 * p]) | ((unsigned)f2bf(e1[2 * p + 1]) << 16);
    }
    acc[0][0] = __builtin_amdgcn_mfma_f32_16x16x32_bf16(a0, b0.v, acc[0][0], 0, 0, 0);
    acc[1][0] = __builtin_amdgcn_mfma_f32_16x16x32_bf16(a1, b0.v, acc[1][0], 0, 0, 0);
    acc[0][1] = __builtin_amdgcn_mfma_f32_16x16x32_bf16(a0, b1.v, acc[0][1], 0, 0, 0);
    acc[1][1] = __builtin_amdgcn_mfma_f32_16x16x32_bf16(a1, b1.v, acc[1][1], 0, 0, 0);
  }

  if (tile < 2) {
    float* out = part1 + (size_t)kc * PSTRIDE1;
#pragma unroll
    for (int mf = 0; mf < 2; ++mf)
#pragma unroll
      for (int nf = 0; nf < 2; ++nf)
#pragma unroll
        for (int j = 0; j < 4; ++j) {
          int m = mf * 16 + kg * 4 + j;
          int n = n0 + wid * 32 + nf * 16 + cl;
          out[m * 512 + n] = acc[mf][nf][j];
        }
  } else {
    float* out = part2 + (size_t)kc * PSTRIDE2;
#pragma unroll
    for (int mf = 0; mf < 2; ++mf)
#pragma unroll
      for (int nf = 0; nf < 2; ++nf)
#pragma unroll
        for (int j = 0; j < 4; ++j) {
          int m = mf * 16 + kg * 4 + j;
          int n = wid * 32 + nf * 16 + cl;
          out[m * 256 + n] = acc[mf][nf][j];
        }
  }
}

// ---------------- reduce split-K partials: 768 blocks, 8 threads/output ----------
__global__ __launch_bounds__(256) void reduce_big(const float* __restrict__ part1,
    const float* __restrict__ part2, const float* __restrict__ b_c1,
    const float* __restrict__ b_r1, float* __restrict__ y1, float* __restrict__ z1) {
  __shared__ float red[8][32];
  int b = blockIdx.x, t = threadIdx.x;
  int oo = t & 31, j = t >> 5;
  float s = 0.f;
  if (b < 512) {
    const float* p = part1 + b * 32 + oo;
    for (int c = j; c < NGK; c += 8) s += p[(size_t)c * PSTRIDE1];
    red[j][oo] = s;
    __syncthreads();
    if (t < 32) {
      float r = 0.f;
#pragma unroll
      for (int jj = 0; jj < 8; ++jj) r += red[jj][t];
      int o = b * 32 + t;
      r += b_c1[o & 511];
      y1[o] = r > 0.f ? r : ALPHA * r;
    }
  } else {
    const float* p = part2 + (b - 512) * 32 + oo;
    for (int c = j; c < NGK; c += 8) s += p[(size_t)c * PSTRIDE2];
    red[j][oo] = s;
    __syncthreads();
    if (t < 32) {
      float r = 0.f;
#pragma unroll
      for (int jj = 0; jj < 8; ++jj) r += red[jj][t];
      int u = (b - 512) * 32 + t;
      r += b_r1[u & 255];
      z1[u] = r > 0.f ? r : ALPHA * r;
    }
  }
}

// ---------------- fully-parallel tail: grid (12 tiles, 32 m) ----------------------
__global__ __launch_bounds__(256) void tail_all(
    const float* __restrict__ y1g, const float* __restrict__ z1g,
    const float* __restrict__ w_c2, const float* __restrict__ b_c2,
    const float* __restrict__ w_co, const float* __restrict__ b_co,
    const float* __restrict__ w_sm, const float* __restrict__ b_sm,
    const float* __restrict__ w_r2, const float* __restrict__ b_r2,
    const float* __restrict__ w_r3, const float* __restrict__ b_r3,
    const float* __restrict__ w_r4, const float* __restrict__ b_r4,
    const float* __restrict__ w_ro, const float* __restrict__ b_ro,
    const float* __restrict__ w_sg, const float* __restrict__ b_sg,
    float* __restrict__ class_out, float* __restrict__ reg_out) {
  int tile = blockIdx.x, m = blockIdx.y, t = threadIdx.x;
  if (tile < 8) {
    __shared__ float ly1[512], ly2[256], ly3[29 * 13];
    ly1[t] = y1g[m * 512 + t];
    ly1[t + 256] = y1g[m * 512 + 256 + t];
    __syncthreads();
    {
      float s = b_c2[t];
      for (int k = 0; k < 512; ++k) s = fmaf(ly1[k], w_c2[k * 256 + t], s);
      ly2[t] = s > 0.f ? s : ALPHA * s;
    }
    __syncthreads();
    int p0 = tile * 29;
    int np = 225 - p0; if (np > 29) np = 29;
    int ncols = np * 13;
    for (int n = t; n < ncols; n += 256) {
      int col = p0 * 13 + n;
      float s = b_co[col];
      for (int k = 0; k < 256; ++k) s = fmaf(ly2[k], w_co[k * 2925 + col], s);
      ly3[n] = s > 0.f ? s : ALPHA * s;
    }
    __syncthreads();
    if (t < np) {
      float v[13], l[13], mx = -1e30f;
#pragma unroll
      for (int i = 0; i < 13; ++i) v[i] = ly3[t * 13 + i];
#pragma unroll
      for (int j = 0; j < 13; ++j) {
        float s = b_sm[j];
#pragma unroll
        for (int i = 0; i < 13; ++i) s = fmaf(v[i], w_sm[i * 13 + j], s);
        l[j] = s; mx = fmaxf(mx, s);
      }
      float sum = 0.f;
#pragma unroll
      for (int j = 0; j < 13; ++j) { l[j] = expf(l[j] - mx); sum += l[j]; }
      float inv = 1.f / sum;
      float* o = class_out + ((size_t)m * 225 + p0 + t) * 13;
#pragma unroll
      for (int j = 0; j < 13; ++j) o[j] = l[j] * inv;
    }
  } else {
    __shared__ float lz1[256], lz2[128], lz3[128], lz4[64], lzo[57 * 4];
    lz1[t] = z1g[m * 256 + t];
    __syncthreads();
    if (t < 128) {
      float s = b_r2[t];
      for (int k = 0; k < 256; ++k) s = fmaf(lz1[k], w_r2[k * 128 + t], s);
      lz2[t] = s > 0.f ? s : ALPHA * s;
    }
    __syncthreads();
    if (t < 128) {
      float s = b_r3[t];
      for (int k = 0; k < 128; ++k) s = fmaf(lz2[k], w_r3[k * 128 + t], s);
      lz3[t] = s > 0.f ? s : ALPHA * s;
    }
    __syncthreads();
    if (t < 64) {
      float s = b_r4[t];
      for (int k = 0; k < 128; ++k) s = fmaf(lz3[k], w_r4[k * 64 + t], s);
      lz4[t] = s > 0.f ? s : ALPHA * s;
    }
    __syncthreads();
    int p0 = (tile - 8) * 57;
    int np = 225 - p0; if (np > 57) np = 57;
    int ncols = np * 4;
    for (int n = t; n < ncols; n += 256) {
      int col = p0 * 4 + n;
      float s = b_ro[col];
#pragma unroll
      for (int k = 0; k < 64; ++k) s = fmaf(lz4[k], w_ro[k * 900 + col], s);
      lzo[n] = s;
    }
    __syncthreads();
    if (t < np) {
      float z[4];
#pragma unroll
      for (int i = 0; i < 4; ++i) z[i] = lzo[t * 4 + i];
      float* ro = reg_out + ((size_t)m * 225 + p0 + t) * 4;
#pragma unroll
      for (int j = 0; j < 4; ++j) {
        float s = b_sg[j];
#pragma unroll
        for (int i = 0; i < 4; ++i) s = fmaf(z[i], w_sg[i * 4 + j], s);
        ro[j] = 1.f / (1.f + expf(-s));
      }
    }
  }
}

// ---------------- workspace layout (bytes) ----------------
#define OFF_P1     ((size_t)0)            // 25,229,312
#define OFF_BPACK  ((size_t)25229312)     // 36,864
#define OFF_H      ((size_t)25266176)     // 11,935,744 (bf16 h)
#define OFF_PART1  ((size_t)37201920)     // 243*16448*4 = 15,987,456
#define OFF_PART2  ((size_t)53189376)     // 243*8256*4  =  8,024,832
#define OFF_Y1     ((size_t)61214208)     // 65,536
#define OFF_Z1     ((size_t)61279744)     // 32,768

extern "C" void kernel_launch(void* const* d_in, const int* in_sizes, int n_in,
                              void* d_out, int out_size, void* d_ws, size_t ws_size,
                              hipStream_t stream) {
  const float* x     = (const float*)d_in[0];
  const float* w1    = (const float*)d_in[1];
  const float* b1    = (const float*)d_in[2];
  const float* w2    = (const float*)d_in[3];
  const float* b2    = (const float*)d_in[4];
  const float* w_c1  = (const float*)d_in[5];
  const float* b_c1  = (const float*)d_in[6];
  const float* w_c2  = (const float*)d_in[7];
  const float* b_c2  = (const float*)d_in[8];
  const float* w_co  = (const float*)d_in[9];
  const float* b_co  = (const float*)d_in[10];
  const float* w_sm  = (const float*)d_in[11];
  const float* b_sm  = (const float*)d_in[12];
  const float* w_r1  = (const float*)d_in[13];
  const float* b_r1  = (const float*)d_in[14];
  const float* w_r2  = (const float*)d_in[15];
  const float* b_r2  = (const float*)d_in[16];
  const float* w_r3  = (const float*)d_in[17];
  const float* b_r3  = (const float*)d_in[18];
  const float* w_r4  = (const float*)d_in[19];
  const float* b_r4  = (const float*)d_in[20];
  const float* w_ro  = (const float*)d_in[21];
  const float* b_ro  = (const float*)d_in[22];
  const float* w_sg  = (const float*)d_in[23];
  const float* b_sg  = (const float*)d_in[24];

  char* ws = (char*)d_ws;
  unsigned short* p1    = (unsigned short*)(ws + OFF_P1);
  unsigned short* bpack = (unsigned short*)(ws + OFF_BPACK);
  unsigned short* hbf   = (unsigned short*)(ws + OFF_H);
  float*          part1 = (float*)(ws + OFF_PART1);
  float*          part2 = (float*)(ws + OFF_PART2);
  float*          y1    = (float*)(ws + OFF_Y1);
  float*          z1    = (float*)(ws + OFF_Z1);

  float* class_out = (float*)d_out;
  float* reg_out   = (float*)d_out + 32 * 225 * 13;

  conv1_pool<<<1540, 256, 0, stream>>>(x, w1, b1, p1);
  repack_w2<<<72, 256, 0, stream>>>(w2, bpack);
  conv2_pool<<<dim3(47, 32), 256, 0, stream>>>(p1, bpack, b2, hbf);
  gemm_mfma<<<dim3(NGK, 3), 512, 0, stream>>>(w_c1, w_r1, hbf, part1, part2);
  reduce_big<<<768, 256, 0, stream>>>(part1, part2, b_c1, b_r1, y1, z1);
  tail_all<<<dim3(12, 32), 256, 0, stream>>>(y1, z1,
      w_c2, b_c2, w_co, b_co, w_sm, b_sm,
      w_r2, b_r2, w_r3, b_r3, w_r4, b_r4,
      w_ro, b_ro, w_sg, b_sg, class_out, reg_out);
}